// Round 4
// baseline (202.827 us; speedup 1.0000x reference)
//
#include <hip/hip_runtime.h>

// KANLayer as one bf16 GEMM: C[8192][1024] = A[8192][7168] * Bt[1024][7168]^T
// (duplicate spline knots folded; base_weight = plane 0).
// GEMM: BM=256 BN=256 BK=64, 8 waves (2Mx4N, per-wave 128x64), 8-phase
// counted-vmcnt schedule, T1 XCD swizzle, T2 LDS XOR swizzle, split-K=2
// (grid 256 = 1 block/CU), f32 atomic-add epilogue.
//
// STAGING REGIONS (the r3 bugfix): regions match the read partition.
//   A-MH h  = rows {h*64..h*64+63} u {128+h*64..128+h*64+63}   (read by wr=h/2.. all waves at MH=h phases)
//   B-NH h  = rows {wc*64+h*32..+31} for wc=0..3               (read at NH=h phases)
// Each wave stages its own 8-row group per inst (wave-uniform LDS base),
// so discontiguous regions stage exactly.

#define IN_F   1024
#define OUT_F  1024
#define K_DIM  (IN_F * 7)    // 7168
#define M_DIM  8192
#define N_DIM  OUT_F
#define K_BLK  (K_DIM / 2)   // 3584 per kz-block
#define NT     (K_BLK / 64)  // 56 K-tiles per block (even -> no tail)

typedef __attribute__((ext_vector_type(8))) __bf16 bf16x8;
typedef __attribute__((ext_vector_type(4))) float f32x4;
typedef __attribute__((ext_vector_type(4))) unsigned short ushort4v;

__device__ inline unsigned short f2bf(float f) {
    union { float f; unsigned int u; } v; v.f = f;
    unsigned int u = v.u;
    return (unsigned short)((u + 0x7FFFu + ((u >> 16) & 1u)) >> 16);  // RNE
}

// --------------------------------------------------------------------------
__global__ void zero_out(float* __restrict__ C) {
    reinterpret_cast<f32x4*>(C)[blockIdx.x * 256 + threadIdx.x] =
        (f32x4){0.f, 0.f, 0.f, 0.f};
}

// --------------------------------------------------------------------------
// fold_w: spline_weight (dup knots summed) + base_weight -> Bt[N][K] bf16.
// --------------------------------------------------------------------------
__global__ void fold_w(const float* __restrict__ sw, const float* __restrict__ bw,
                       unsigned short* __restrict__ Bt) {
    int idx = blockIdx.x * 256 + threadIdx.x;       // o*1024 + i
    const float4* p = reinterpret_cast<const float4*>(sw + (size_t)idx * 12);
    float4 a = p[0];
    float4 b = p[1];
    float4 c = p[2];
    int o = idx >> 10, i = idx & 1023;
    size_t base = (size_t)o * K_DIM + i;
    Bt[base         ] = f2bf(bw[idx]);
    Bt[base + 1*1024] = f2bf(a.x + a.y + a.z + a.w);
    Bt[base + 2*1024] = f2bf(b.x);
    Bt[base + 3*1024] = f2bf(b.y);
    Bt[base + 4*1024] = f2bf(b.z);
    Bt[base + 5*1024] = f2bf(b.w);
    Bt[base + 6*1024] = f2bf(c.x + c.y + c.z + c.w);
}

// --------------------------------------------------------------------------
// expand_x: x -> A[M][K] bf16. Plane 0 = x; planes 1..6 = hat_j(clip(x)).
// --------------------------------------------------------------------------
__global__ void expand_x(const float* __restrict__ x, unsigned short* __restrict__ Ax) {
    int idx = blockIdx.x * 256 + threadIdx.x;       // m*256 + i4
    int m = idx >> 8, i4 = idx & 255;
    float4 v = reinterpret_cast<const float4*>(x)[idx];
    float vv[4] = {v.x, v.y, v.z, v.w};
    size_t base = (size_t)m * K_DIM + i4 * 4;

    ushort4v s;
    #pragma unroll
    for (int e = 0; e < 4; ++e) s[e] = f2bf(vv[e]);
    *reinterpret_cast<ushort4v*>(Ax + base) = s;

    float xc[4];
    #pragma unroll
    for (int e = 0; e < 4; ++e) xc[e] = fminf(fmaxf(vv[e], -1.0f), 1.0f);

    #pragma unroll
    for (int j = 0; j < 6; ++j) {
        float t = -1.0f + 0.4f * (float)j;
        #pragma unroll
        for (int e = 0; e < 4; ++e)
            s[e] = f2bf(fmaxf(1.0f - fabsf((xc[e] - t) * 2.5f), 0.0f));
        *reinterpret_cast<ushort4v*>(Ax + base + (size_t)(j + 1) * 1024) = s;
    }
}

// --------------------------------------------------------------------------
// 8-phase split-K GEMM. LDS: As 2x[256][64], Bs 2x[256][64] (128 KiB),
// XOR-swizzled (byte ^= (row&7)<<4) via pre-swizzled global source.
//
// Read windows (block-wide, buf0): A-MH0 @p1,p2; A-MH1 @p3,p4;
// B-NH0 @p1,p3; B-NH1 @p2,p4. buf1 the same at p5..p8.
// Stage ledger (issue phase -> region; always after that region's last read,
// barrier-ordered; deadline = first re-read):
//  p1: A-MH1(buf1,t1)  [free after prev p8; needed p7]      slack 6
//  p2: B-NH1(buf1,t1)  [free after prev p8; needed p6]      slack 4
//  p3: A-MH0(buf0,t2)  [free after p2;      needed next p1] slack 6
//  p4: B-NH0(buf0,t2)  [free after p3;      needed next p1] slack 5  VM(4)
//  p5: A-MH1(buf0,t2)  [free after p4;      needed next p3] slack 6
//  p6: B-NH1(buf0,t2)  [free after p4;      needed next p2] slack 4
//  p7: A-MH0(buf1,t3)  [free after p6;      needed next p5] slack 6
//  p8: B-NH0(buf1,t3)  [free after p7;      needed next p5] slack 5  VM(4)
// vmcnt(4)@p4: leaves p3,p4 in flight -> prev p7,p8 + p1,p2 landed ->
//   everything p5..p8 reads is resident.
// vmcnt(4)@p8: leaves p7,p8 in flight -> p3..p6 landed -> everything next
//   p1..p4 reads is resident. Never drains to 0 (4-12 insts outstanding).
// Last-iter prefetches clamp to NT-1: stale data into never-again-read
// regions, same ordering -> harmless.
// --------------------------------------------------------------------------
__global__ __launch_bounds__(512, 2) void gemm_sk(
        const unsigned short* __restrict__ Ag,   // [M][K] bf16
        const unsigned short* __restrict__ Bg,   // [N][K] bf16
        float* __restrict__ C) {                 // [M][N] f32 (pre-zeroed)
    __shared__ unsigned short As[2][256 * 64];   // 64 KiB
    __shared__ unsigned short Bs[2][256 * 64];   // 64 KiB

    const int tid  = threadIdx.x;
    const int wave = tid >> 6;
    const int lane = tid & 63;
    const int wr   = wave >> 2;   // 0..1 (M: 128 rows each)
    const int wc   = wave & 3;    // 0..3 (N: 64 cols each)

    // T1: bijective XCD swizzle (nwg = 256, divisible by 8)
    const int orig = blockIdx.x;
    const int wg   = ((orig & 7) << 5) | (orig >> 3);
    const int bx   = wg & 3;          // N tile (BN=256)
    const int by   = (wg >> 2) & 31;  // M tile (BM=256)
    const int kz   = wg >> 7;         // K half
    const size_t k0 = (size_t)kz * K_BLK;

    // pre-swizzled global column (bytes); row&7 == (tid>>3)&7 for all stages
    const int scol = ((tid & 7) * 16) ^ (((tid >> 3) & 7) << 4);

// A-MH h: inst0 -> rows h*64 + (tid>>3); inst1 -> rows 128 + h*64 + (tid>>3)
// LDS dest (shorts): h*4096 + wave*512 ; 8192 + h*4096 + wave*512
#define STAGE_A(BUF, H, T) do {                                                 \
    int kt_ = ((T) < NT ? (T) : NT - 1) * 64;                                   \
    const unsigned short* g0_ = Ag + (size_t)(by * 256 + (H) * 64 + (tid >> 3)) * K_DIM + k0 + kt_ + (scol >> 1); \
    const unsigned short* g1_ = Ag + (size_t)(by * 256 + 128 + (H) * 64 + (tid >> 3)) * K_DIM + k0 + kt_ + (scol >> 1); \
    __builtin_amdgcn_global_load_lds((const __attribute__((address_space(1))) void*)g0_, \
        (__attribute__((address_space(3))) void*)(As[BUF] + (H) * 4096 + wave * 512), 16, 0, 0); \
    __builtin_amdgcn_global_load_lds((const __attribute__((address_space(1))) void*)g1_, \
        (__attribute__((address_space(3))) void*)(As[BUF] + 8192 + (H) * 4096 + wave * 512), 16, 0, 0); \
} while (0)

// B-NH h: inst0 -> rows (tid>>8)*64 + h*32 + ((tid>>3)&31); inst1 -> +128
// LDS dest (shorts): (wave>>2)*4096 + h*2048 + (wave&3)*512 ; +8192
#define STAGE_B(BUF, H, T) do {                                                 \
    int kt_ = ((T) < NT ? (T) : NT - 1) * 64;                                   \
    const unsigned short* g0_ = Bg + (size_t)(bx * 256 + (tid >> 8) * 64 + (H) * 32 + ((tid >> 3) & 31)) * K_DIM + k0 + kt_ + (scol >> 1); \
    const unsigned short* g1_ = Bg + (size_t)(bx * 256 + 128 + (tid >> 8) * 64 + (H) * 32 + ((tid >> 3) & 31)) * K_DIM + k0 + kt_ + (scol >> 1); \
    __builtin_amdgcn_global_load_lds((const __attribute__((address_space(1))) void*)g0_, \
        (__attribute__((address_space(3))) void*)(Bs[BUF] + (wave >> 2) * 4096 + (H) * 2048 + (wave & 3) * 512), 16, 0, 0); \
    __builtin_amdgcn_global_load_lds((const __attribute__((address_space(1))) void*)g1_, \
        (__attribute__((address_space(3))) void*)(Bs[BUF] + 8192 + (wave >> 2) * 4096 + (H) * 2048 + (wave & 3) * 512), 16, 0, 0); \
} while (0)

#define VMW4 asm volatile("s_waitcnt vmcnt(4)" ::: "memory")
#define VM_NONE (void)0

#define PHASE(BUF, MH, NH, STAGE, VMW) do {                                     \
    bf16x8 af[8], bfr[4];                                                       \
    _Pragma("unroll")                                                           \
    for (int m2 = 0; m2 < 4; ++m2)                                              \
        _Pragma("unroll")                                                       \
        for (int kk = 0; kk < 2; ++kk) {                                        \
            int row = wr * 128 + (MH) * 64 + m2 * 16 + (lane & 15);             \
            int off = ((row << 7) + kk * 64 + (lane >> 4) * 16) ^ ((row & 7) << 4); \
            af[m2 * 2 + kk] = *reinterpret_cast<const bf16x8*>((const char*)As[BUF] + off); \
        }                                                                       \
    _Pragma("unroll")                                                           \
    for (int n2 = 0; n2 < 2; ++n2)                                              \
        _Pragma("unroll")                                                       \
        for (int kk = 0; kk < 2; ++kk) {                                        \
            int row = wc * 64 + (NH) * 32 + n2 * 16 + (lane & 15);              \
            int off = ((row << 7) + kk * 64 + (lane >> 4) * 16) ^ ((row & 7) << 4); \
            bfr[n2 * 2 + kk] = *reinterpret_cast<const bf16x8*>((const char*)Bs[BUF] + off); \
        }                                                                       \
    STAGE;                                                                      \
    VMW;                                                                        \
    __builtin_amdgcn_s_barrier();                                               \
    asm volatile("s_waitcnt lgkmcnt(0)");                                       \
    __builtin_amdgcn_s_setprio(1);                                              \
    _Pragma("unroll")                                                           \
    for (int m2 = 0; m2 < 4; ++m2)                                              \
        _Pragma("unroll")                                                       \
        for (int n2 = 0; n2 < 2; ++n2)                                          \
            _Pragma("unroll")                                                   \
            for (int kk = 0; kk < 2; ++kk)                                      \
                acc[(MH) * 4 + m2][(NH) * 2 + n2] =                             \
                    __builtin_amdgcn_mfma_f32_16x16x32_bf16(                    \
                        af[m2 * 2 + kk], bfr[n2 * 2 + kk],                      \
                        acc[(MH) * 4 + m2][(NH) * 2 + n2], 0, 0, 0);            \
    __builtin_amdgcn_s_setprio(0);                                              \
    __builtin_amdgcn_s_barrier();                                               \
} while (0)

    f32x4 acc[8][4];
    const f32x4 zero = {0.f, 0.f, 0.f, 0.f};
    #pragma unroll
    for (int m = 0; m < 8; ++m)
        #pragma unroll
        for (int n = 0; n < 4; ++n) acc[m][n] = zero;

    // prologue: t0 full (A-MH0,B-NH0,A-MH1,B-NH1 -> buf0) + t1 A-MH0,B-NH0
    // -> buf1. vmcnt(4): t0's 8 insts landed, t1's 4 in flight (= steady
    // state's "prev p7, prev p8" queue).
    STAGE_A(0, 0, 0); STAGE_B(0, 0, 0); STAGE_A(0, 1, 0); STAGE_B(0, 1, 0);
    STAGE_A(1, 0, 1); STAGE_B(1, 0, 1);
    asm volatile("s_waitcnt vmcnt(4)" ::: "memory");
    __builtin_amdgcn_s_barrier();

    for (int i = 0; i < NT / 2; ++i) {
        const int t1 = 2 * i + 1, t2 = 2 * i + 2, t3 = 2 * i + 3;
        PHASE(0, 0, 0, STAGE_A(1, 1, t1), VM_NONE);
        PHASE(0, 0, 1, STAGE_B(1, 1, t1), VM_NONE);
        PHASE(0, 1, 0, STAGE_A(0, 0, t2), VM_NONE);
        PHASE(0, 1, 1, STAGE_B(0, 0, t2), VMW4);
        PHASE(1, 0, 0, STAGE_A(0, 1, t2), VM_NONE);
        PHASE(1, 0, 1, STAGE_B(0, 1, t2), VM_NONE);
        PHASE(1, 1, 0, STAGE_A(1, 0, t3), VM_NONE);
        PHASE(1, 1, 1, STAGE_B(1, 0, t3), VMW4);
    }

    // epilogue: atomic accumulate (split-K).
    // m = MH*4+m2 -> row = wr*128 + (m>>2)*64 + (m&3)*16
    // n = NH*2+n2 -> col = wc*64 + (n>>1)*32 + (n&1)*16
    // C/D layout (verified): col = lane&15, row = (lane>>4)*4 + r
    #pragma unroll
    for (int m = 0; m < 8; ++m) {
        #pragma unroll
        for (int n = 0; n < 4; ++n) {
            const int row = by * 256 + wr * 128 + (m >> 2) * 64 + (m & 3) * 16 + ((lane >> 4) << 2);
            const int col = bx * 256 + wc * 64 + (n >> 1) * 32 + (n & 1) * 16 + (lane & 15);
            #pragma unroll
            for (int r = 0; r < 4; ++r)
                unsafeAtomicAdd(&C[(size_t)(row + r) * N_DIM + col], acc[m][n][r]);
        }
    }
#undef STAGE_A
#undef STAGE_B
#undef VMW4
#undef VM_NONE
#undef PHASE
}

// --------------------------------------------------------------------------
extern "C" void kernel_launch(void* const* d_in, const int* in_sizes, int n_in,
                              void* d_out, int out_size, void* d_ws, size_t ws_size,
                              hipStream_t stream) {
    const float* x  = (const float*)d_in[0];   // (4,2048,1024) f32
    const float* sw = (const float*)d_in[1];   // (1024,1024,12) f32
    const float* bw = (const float*)d_in[2];   // (1024,1024) f32
    float* out = (float*)d_out;                // (4,2048,1024) f32

    unsigned short* Ax = (unsigned short*)d_ws;                                      // 117.4 MB
    unsigned short* Bt = (unsigned short*)((char*)d_ws + (size_t)M_DIM * K_DIM * 2); // 14.7 MB

    zero_out<<<(M_DIM * N_DIM / 4) / 256, 256, 0, stream>>>(out);
    fold_w<<<(OUT_F * IN_F) / 256, 256, 0, stream>>>(sw, bw, Bt);
    expand_x<<<(M_DIM * IN_F / 4) / 256, 256, 0, stream>>>(x, Ax);

    gemm_sk<<<256, 512, 0, stream>>>(Ax, Bt, out);
}

// Round 5
// 186.868 us; speedup vs baseline: 1.0854x; 1.0854x over previous
//
#include <hip/hip_runtime.h>

// KANLayer as one bf16 GEMM: C[8192][1024] = A[8192][7168] * Bt[1024][7168]^T
// (duplicate spline knots folded; base_weight = plane 0).
// GEMM: BM=256 BN=256 BK=64, 8 waves (2Mx4N, per-wave 128x64), 8-phase
// schedule with UNIFORM vmcnt(8) + >=5-phase stage->read distance (r5 fix),
// A-fragment reuse across NH pair, T1 XCD swizzle, T2 LDS XOR swizzle,
// split-K=2 (grid 256 = 1 block/CU), f32 atomic-add epilogue.

#define IN_F   1024
#define OUT_F  1024
#define K_DIM  (IN_F * 7)    // 7168
#define M_DIM  8192
#define N_DIM  OUT_F
#define K_BLK  (K_DIM / 2)   // 3584 per kz-block
#define NT     (K_BLK / 64)  // 56 K-tiles per block (even -> no tail)

typedef __attribute__((ext_vector_type(8))) __bf16 bf16x8;
typedef __attribute__((ext_vector_type(4))) float f32x4;
typedef __attribute__((ext_vector_type(4))) unsigned short ushort4v;

__device__ inline unsigned short f2bf(float f) {
    union { float f; unsigned int u; } v; v.f = f;
    unsigned int u = v.u;
    return (unsigned short)((u + 0x7FFFu + ((u >> 16) & 1u)) >> 16);  // RNE
}

// --------------------------------------------------------------------------
__global__ void zero_out(float* __restrict__ C) {
    reinterpret_cast<f32x4*>(C)[blockIdx.x * 256 + threadIdx.x] =
        (f32x4){0.f, 0.f, 0.f, 0.f};
}

// --------------------------------------------------------------------------
// fold_w: spline_weight (dup knots summed) + base_weight -> Bt[N][K] bf16.
// --------------------------------------------------------------------------
__global__ void fold_w(const float* __restrict__ sw, const float* __restrict__ bw,
                       unsigned short* __restrict__ Bt) {
    int idx = blockIdx.x * 256 + threadIdx.x;       // o*1024 + i
    const float4* p = reinterpret_cast<const float4*>(sw + (size_t)idx * 12);
    float4 a = p[0];
    float4 b = p[1];
    float4 c = p[2];
    int o = idx >> 10, i = idx & 1023;
    size_t base = (size_t)o * K_DIM + i;
    Bt[base         ] = f2bf(bw[idx]);
    Bt[base + 1*1024] = f2bf(a.x + a.y + a.z + a.w);
    Bt[base + 2*1024] = f2bf(b.x);
    Bt[base + 3*1024] = f2bf(b.y);
    Bt[base + 4*1024] = f2bf(b.z);
    Bt[base + 5*1024] = f2bf(b.w);
    Bt[base + 6*1024] = f2bf(c.x + c.y + c.z + c.w);
}

// --------------------------------------------------------------------------
// expand_x: x -> A[M][K] bf16. Plane 0 = x; planes 1..6 = hat_j(clip(x)).
// --------------------------------------------------------------------------
__global__ void expand_x(const float* __restrict__ x, unsigned short* __restrict__ Ax) {
    int idx = blockIdx.x * 256 + threadIdx.x;       // m*256 + i4
    int m = idx >> 8, i4 = idx & 255;
    float4 v = reinterpret_cast<const float4*>(x)[idx];
    float vv[4] = {v.x, v.y, v.z, v.w};
    size_t base = (size_t)m * K_DIM + i4 * 4;

    ushort4v s;
    #pragma unroll
    for (int e = 0; e < 4; ++e) s[e] = f2bf(vv[e]);
    *reinterpret_cast<ushort4v*>(Ax + base) = s;

    float xc[4];
    #pragma unroll
    for (int e = 0; e < 4; ++e) xc[e] = fminf(fmaxf(vv[e], -1.0f), 1.0f);

    #pragma unroll
    for (int j = 0; j < 6; ++j) {
        float t = -1.0f + 0.4f * (float)j;
        #pragma unroll
        for (int e = 0; e < 4; ++e)
            s[e] = f2bf(fmaxf(1.0f - fabsf((xc[e] - t) * 2.5f), 0.0f));
        *reinterpret_cast<ushort4v*>(Ax + base + (size_t)(j + 1) * 1024) = s;
    }
}

// --------------------------------------------------------------------------
// 8-phase split-K GEMM. LDS: As 2x[256][64], Bs 2x[256][64] (128 KiB),
// XOR-swizzled (byte ^= (row&7)<<4) via pre-swizzled global source.
//
// Regions: A-MH h = rows {h*64..} u {128+h*64..}; B-NH h = per-wc 32-row
// blocks. Read windows (buf0): A-MH0 @p1,p2; A-MH1 @p3,p4; B-NH0 @p1,p3;
// B-NH1 @p2,p4; buf1 same at p5..p8.
//
// Stage ledger (issue -> region [free-after | first-read | distance]):
//  p1: B-NH1(buf1,t1) [prev-p8 | p6     | 5]
//  p2: A-MH1(buf1,t1) [prev-p8 | p7     | 5]
//  p3: A-MH0(buf0,t2) [p2      | nxt-p1 | 6]
//  p4: B-NH0(buf0,t2) [p3      | nxt-p1 | 5]
//  p5: B-NH1(buf0,t2) [p4      | nxt-p2 | 5]
//  p6: A-MH1(buf0,t2) [p4      | nxt-p3 | 5]
//  p7: A-MH0(buf1,t3) [p6      | nxt-p5 | 6]
//  p8: B-NH0(buf1,t3) [p7      | nxt-p5 | 5]
// Uniform vmcnt(8) at EVERY phase (after stage, before barrier): with 2
// loads/phase this forces completion of the stage issued 4 phases earlier
// -> every region resident >=1 phase before its first ds_read, and each
// wait targets a ~2000-cycle-old load (no stall). Outstanding stays 8-12,
// never drains to 0. Last-iter clamped stages land in never-again-read
// regions after their last read (barrier-ordered) — harmless.
// --------------------------------------------------------------------------
__global__ __launch_bounds__(512, 2) void gemm_sk(
        const unsigned short* __restrict__ Ag,   // [M][K] bf16
        const unsigned short* __restrict__ Bg,   // [N][K] bf16
        float* __restrict__ C) {                 // [M][N] f32 (pre-zeroed)
    __shared__ unsigned short As[2][256 * 64];   // 64 KiB
    __shared__ unsigned short Bs[2][256 * 64];   // 64 KiB

    const int tid  = threadIdx.x;
    const int wave = tid >> 6;
    const int lane = tid & 63;
    const int wr   = wave >> 2;   // 0..1 (M: 128 rows each)
    const int wc   = wave & 3;    // 0..3 (N: 64 cols each)

    // T1: bijective XCD swizzle (nwg = 256, divisible by 8)
    const int orig = blockIdx.x;
    const int wg   = ((orig & 7) << 5) | (orig >> 3);
    const int bx   = wg & 3;          // N tile (BN=256)
    const int by   = (wg >> 2) & 31;  // M tile (BM=256)
    const int kz   = wg >> 7;         // K half
    const size_t k0 = (size_t)kz * K_BLK;

    // pre-swizzled global column (bytes); row&7 == (tid>>3)&7 for all stages
    const int scol = ((tid & 7) * 16) ^ (((tid >> 3) & 7) << 4);

// A-MH h: inst0 -> rows h*64 + (tid>>3); inst1 -> rows 128 + h*64 + (tid>>3)
#define STAGE_A(BUF, H, T) do {                                                 \
    int kt_ = ((T) < NT ? (T) : NT - 1) * 64;                                   \
    const unsigned short* g0_ = Ag + (size_t)(by * 256 + (H) * 64 + (tid >> 3)) * K_DIM + k0 + kt_ + (scol >> 1); \
    const unsigned short* g1_ = Ag + (size_t)(by * 256 + 128 + (H) * 64 + (tid >> 3)) * K_DIM + k0 + kt_ + (scol >> 1); \
    __builtin_amdgcn_global_load_lds((const __attribute__((address_space(1))) void*)g0_, \
        (__attribute__((address_space(3))) void*)(As[BUF] + (H) * 4096 + wave * 512), 16, 0, 0); \
    __builtin_amdgcn_global_load_lds((const __attribute__((address_space(1))) void*)g1_, \
        (__attribute__((address_space(3))) void*)(As[BUF] + 8192 + (H) * 4096 + wave * 512), 16, 0, 0); \
} while (0)

// B-NH h: inst0 -> rows (tid>>8)*64 + h*32 + ((tid>>3)&31); inst1 -> +128
#define STAGE_B(BUF, H, T) do {                                                 \
    int kt_ = ((T) < NT ? (T) : NT - 1) * 64;                                   \
    const unsigned short* g0_ = Bg + (size_t)(bx * 256 + (tid >> 8) * 64 + (H) * 32 + ((tid >> 3) & 31)) * K_DIM + k0 + kt_ + (scol >> 1); \
    const unsigned short* g1_ = Bg + (size_t)(bx * 256 + 128 + (tid >> 8) * 64 + (H) * 32 + ((tid >> 3) & 31)) * K_DIM + k0 + kt_ + (scol >> 1); \
    __builtin_amdgcn_global_load_lds((const __attribute__((address_space(1))) void*)g0_, \
        (__attribute__((address_space(3))) void*)(Bs[BUF] + (wave >> 2) * 4096 + (H) * 2048 + (wave & 3) * 512), 16, 0, 0); \
    __builtin_amdgcn_global_load_lds((const __attribute__((address_space(1))) void*)g1_, \
        (__attribute__((address_space(3))) void*)(Bs[BUF] + 8192 + (wave >> 2) * 4096 + (H) * 2048 + (wave & 3) * 512), 16, 0, 0); \
} while (0)

#define PHASE_TAIL(MH, NH)                                                      \
    asm volatile("s_waitcnt vmcnt(8)" ::: "memory");                            \
    __builtin_amdgcn_s_barrier();                                               \
    asm volatile("s_waitcnt lgkmcnt(0)");                                       \
    __builtin_amdgcn_s_setprio(1);                                              \
    _Pragma("unroll")                                                           \
    for (int m2 = 0; m2 < 4; ++m2)                                              \
        _Pragma("unroll")                                                       \
        for (int n2 = 0; n2 < 2; ++n2)                                          \
            _Pragma("unroll")                                                   \
            for (int kk = 0; kk < 2; ++kk)                                      \
                acc[(MH) * 4 + m2][(NH) * 2 + n2] =                             \
                    __builtin_amdgcn_mfma_f32_16x16x32_bf16(                    \
                        af[m2 * 2 + kk], bfr[n2 * 2 + kk],                      \
                        acc[(MH) * 4 + m2][(NH) * 2 + n2], 0, 0, 0);            \
    __builtin_amdgcn_s_setprio(0);                                              \
    __builtin_amdgcn_s_barrier()

// NH=0 phase of the pair: load af (8) + bf (4), then tail.
#define PHASE_A(BUF, MH, STAGE) do {                                            \
    _Pragma("unroll")                                                           \
    for (int m2 = 0; m2 < 4; ++m2)                                              \
        _Pragma("unroll")                                                       \
        for (int kk = 0; kk < 2; ++kk) {                                        \
            int row = wr * 128 + (MH) * 64 + m2 * 16 + (lane & 15);             \
            int off = ((row << 7) + kk * 64 + (lane >> 4) * 16) ^ ((row & 7) << 4); \
            af[m2 * 2 + kk] = *reinterpret_cast<const bf16x8*>((const char*)As[BUF] + off); \
        }                                                                       \
    bf16x8 bfr[4];                                                              \
    _Pragma("unroll")                                                           \
    for (int n2 = 0; n2 < 2; ++n2)                                              \
        _Pragma("unroll")                                                       \
        for (int kk = 0; kk < 2; ++kk) {                                        \
            int row = wc * 64 + n2 * 16 + (lane & 15);                          \
            int off = ((row << 7) + kk * 64 + (lane >> 4) * 16) ^ ((row & 7) << 4); \
            bfr[n2 * 2 + kk] = *reinterpret_cast<const bf16x8*>((const char*)Bs[BUF] + off); \
        }                                                                       \
    STAGE;                                                                      \
    PHASE_TAIL(MH, 0);                                                          \
} while (0)

// NH=1 phase of the pair: af reused from registers; load bf (4) only.
#define PHASE_B(BUF, MH, STAGE) do {                                            \
    bf16x8 bfr[4];                                                              \
    _Pragma("unroll")                                                           \
    for (int n2 = 0; n2 < 2; ++n2)                                              \
        _Pragma("unroll")                                                       \
        for (int kk = 0; kk < 2; ++kk) {                                        \
            int row = wc * 64 + 32 + n2 * 16 + (lane & 15);                     \
            int off = ((row << 7) + kk * 64 + (lane >> 4) * 16) ^ ((row & 7) << 4); \
            bfr[n2 * 2 + kk] = *reinterpret_cast<const bf16x8*>((const char*)Bs[BUF] + off); \
        }                                                                       \
    STAGE;                                                                      \
    PHASE_TAIL(MH, 1);                                                          \
} while (0)

    f32x4 acc[8][4];
    const f32x4 zero = {0.f, 0.f, 0.f, 0.f};
    #pragma unroll
    for (int m = 0; m < 8; ++m)
        #pragma unroll
        for (int n = 0; n < 4; ++n) acc[m][n] = zero;

    // prologue: buf0 <- t0 all 4 regions (8 loads); buf1 <- t1 A-MH0,B-NH0
    // (4 loads). vmcnt(4): buf0 resident, t1's 4 in flight (forced complete
    // by in-loop vmcnt(8) at p3/p4, first read p5).
    STAGE_A(0, 0, 0); STAGE_B(0, 0, 0); STAGE_B(0, 1, 0); STAGE_A(0, 1, 0);
    STAGE_A(1, 0, 1); STAGE_B(1, 0, 1);
    asm volatile("s_waitcnt vmcnt(4)" ::: "memory");
    __builtin_amdgcn_s_barrier();

    for (int i = 0; i < NT / 2; ++i) {
        const int t1 = 2 * i + 1, t2 = 2 * i + 2, t3 = 2 * i + 3;
        bf16x8 af[8];
        PHASE_A(0, 0, STAGE_B(1, 1, t1));   // p1
        PHASE_B(0, 0, STAGE_A(1, 1, t1));   // p2
        PHASE_A(0, 1, STAGE_A(0, 0, t2));   // p3
        PHASE_B(0, 1, STAGE_B(0, 0, t2));   // p4
        PHASE_A(1, 0, STAGE_B(0, 1, t2));   // p5
        PHASE_B(1, 0, STAGE_A(0, 1, t2));   // p6
        PHASE_A(1, 1, STAGE_A(1, 0, t3));   // p7
        PHASE_B(1, 1, STAGE_B(1, 0, t3));   // p8
    }

    // epilogue: atomic accumulate (split-K).
    // m = MH*4+m2 -> row = wr*128 + (m>>2)*64 + (m&3)*16
    // n = NH*2+n2 -> col = wc*64 + (n>>1)*32 + (n&1)*16
    // C/D layout (verified): col = lane&15, row = (lane>>4)*4 + r
    #pragma unroll
    for (int m = 0; m < 8; ++m) {
        #pragma unroll
        for (int n = 0; n < 4; ++n) {
            const int row = by * 256 + wr * 128 + (m >> 2) * 64 + (m & 3) * 16 + ((lane >> 4) << 2);
            const int col = bx * 256 + wc * 64 + (n >> 1) * 32 + (n & 1) * 16 + (lane & 15);
            #pragma unroll
            for (int r = 0; r < 4; ++r)
                unsafeAtomicAdd(&C[(size_t)(row + r) * N_DIM + col], acc[m][n][r]);
        }
    }
#undef STAGE_A
#undef STAGE_B
#undef PHASE_TAIL
#undef PHASE_A
#undef PHASE_B
}

// --------------------------------------------------------------------------
extern "C" void kernel_launch(void* const* d_in, const int* in_sizes, int n_in,
                              void* d_out, int out_size, void* d_ws, size_t ws_size,
                              hipStream_t stream) {
    const float* x  = (const float*)d_in[0];   // (4,2048,1024) f32
    const float* sw = (const float*)d_in[1];   // (1024,1024,12) f32
    const float* bw = (const float*)d_in[2];   // (1024,1024) f32
    float* out = (float*)d_out;                // (4,2048,1024) f32

    unsigned short* Ax = (unsigned short*)d_ws;                                      // 117.4 MB
    unsigned short* Bt = (unsigned short*)((char*)d_ws + (size_t)M_DIM * K_DIM * 2); // 14.7 MB

    zero_out<<<(M_DIM * N_DIM / 4) / 256, 256, 0, stream>>>(out);
    fold_w<<<(OUT_F * IN_F) / 256, 256, 0, stream>>>(sw, bw, Bt);
    expand_x<<<(M_DIM * IN_F / 4) / 256, 256, 0, stream>>>(x, Ax);

    gemm_sk<<<256, 512, 0, stream>>>(Ax, Bt, out);
}